// Round 10
// baseline (441.826 us; speedup 1.0000x reference)
//
#include <hip/hip_runtime.h>
#include <math.h>

// MiniTransformer, round 8: wave-independent MFMA pipeline, zero in-loop barriers.
// Block = 512 thr (8 waves), 2 blocks/CU (LDS ~74KB), 4 waves/SIMD.
// Each WAVE owns 4 groups (16 tokens) per tile iteration:
//   Phase A: per-lane A-frag load direct from global (token=c16, dims 8p+j /
//            32+8p+j), LN1 stats via shfl_xor(16/32) -> a0/a1 bf16 in regs.
//   qkv: 24 MFMA vs LDS-staged ipw' (LN1-gamma folded), bias' adds.
//   attention: wave-local shfl butterfly + softmax + row-0 ctx (as r7).
//   Epilogue per wave via 1KB wave-private LDS relayout buffer (DS ops are
//   in-order per wave -> no barriers): out-proj (8 MFMA) -> LN2 (gamma/beta
//   folded into w1'/b1') -> FFN1 (16 MFMA) + GELU -> FFN2 (16 MFMA) -> store.
// LN fold: qkv(LN1(x)) = xhat·(W⊙γ1)^T + (ipb + W·β1); FFN1(LN2(x)) likewise.
// Weights LDS XOR-swizzled byte^=(row&7)<<4, same involution both sides.

typedef __attribute__((ext_vector_type(8))) short   short8;
typedef __attribute__((ext_vector_type(4))) float   f32x4;
typedef __attribute__((ext_vector_type(4))) unsigned short us4;

#define MFMA16(a,b,c) __builtin_amdgcn_mfma_f32_16x16x32_bf16((a),(b),(c),0,0,0)
#define SWZ(b_, r_) (((unsigned)(b_)) ^ ((((unsigned)(r_)) & 7u) << 4))

__device__ __forceinline__ unsigned short f2bf(float f){
  union { float f; unsigned u; } v; v.f = f;
  unsigned r = v.u + 0x7FFFu + ((v.u >> 16) & 1u);   // RNE
  return (unsigned short)(r >> 16);
}

__device__ __forceinline__ float fast_gelu(float a){
  // exact-erf GELU via A&S 7.1.26 (|err| < 1.5e-7)
  float y = a * 0.70710678118654752f;
  float z = fabsf(y);
  float t = __frcp_rn(fmaf(0.3275911f, z, 1.f));
  float poly = t * fmaf(t, fmaf(t, fmaf(t, fmaf(t, 1.061405429f, -1.453152027f),
                                        1.421413741f), -0.284496736f), 0.254829592f);
  float e = __expf(-y * y);
  float erfz = 1.f - poly * e;
  float erfy = (y < 0.f) ? -erfz : erfz;
  return 0.5f * a * (1.f + erfy);
}

__global__ __launch_bounds__(512)
__attribute__((amdgpu_waves_per_eu(4, 4)))
void mt_kernel(const float* __restrict__ z_m, const float* __restrict__ z_c,
               const float* __restrict__ z_t, const float* __restrict__ z_cls,
               const float* __restrict__ ipw, const float* __restrict__ ipb,
               const float* __restrict__ out_w, const float* __restrict__ out_b,
               const float* __restrict__ ln1_g, const float* __restrict__ ln1_b,
               const float* __restrict__ ln2_g, const float* __restrict__ ln2_b,
               const float* __restrict__ w1, const float* __restrict__ b1,
               const float* __restrict__ w2, const float* __restrict__ b2,
               float* __restrict__ h_out, float* __restrict__ aw_out, int M)
{
  __shared__ unsigned short ipw_s[192*64];   // 24.0 KB  (ipw · diag(ln1_g))
  __shared__ unsigned short ow_s [64*64];    //  8.0 KB
  __shared__ unsigned short w1_s [128*64];   // 16.0 KB  (w1 · diag(ln2_g))
  __shared__ unsigned short w2_s [64*128];   // 16.0 KB
  __shared__ float          par_s[448];      //  1.75 KB: [0,192)=ipb', [192,256)=z_cls+out_b,
                                             //           [256,384)=b1', [384,448)=b2
  __shared__ unsigned short wbuf_s[8][512];  //  8.0 KB: per-wave relayout buffer
                                             //  total ~73.75 KB -> 2 blocks/CU

  const int tid = threadIdx.x;

  // ---------------- one-time staging (per block) ----------------
  for (int i = tid; i < 192*64; i += 512){
    int row = i >> 6;
    ipw_s[SWZ((unsigned)i*2u, row) >> 1] = f2bf(ipw[i] * ln1_g[i & 63]);
  }
  for (int i = tid; i < 64*64; i += 512){
    int row = i >> 6;
    ow_s[SWZ((unsigned)i*2u, row) >> 1] = f2bf(out_w[i]);
  }
  for (int i = tid; i < 128*64; i += 512){
    int row = i >> 6;
    w1_s[SWZ((unsigned)i*2u, row) >> 1] = f2bf(w1[i] * ln2_g[i & 63]);
  }
  for (int i = tid; i < 64*128; i += 512){
    int row = i >> 7;
    w2_s[SWZ((unsigned)i*2u, row) >> 1] = f2bf(w2[i]);
  }
  for (int i = tid; i < 448; i += 512){
    float v;
    if (i < 192){                              // ipb' = ipb + ipw·ln1_b
      float a = ipb[i];
      const float* wr = ipw + (size_t)i * 64;
      #pragma unroll 4
      for (int d = 0; d < 64; ++d) a = fmaf(wr[d], ln1_b[d], a);
      v = a;
    } else if (i < 256){                       // zcob = z_cls + out_b
      v = z_cls[i-192] + out_b[i-192];
    } else if (i < 384){                       // b1' = b1 + w1·ln2_b
      int e = i - 256;
      float a = b1[e];
      const float* wr = w1 + (size_t)e * 64;
      #pragma unroll 4
      for (int d = 0; d < 64; ++d) a = fmaf(wr[d], ln2_b[d], a);
      v = a;
    } else {
      v = b2[i-384];
    }
    par_s[i] = v;
  }
  __syncthreads();                             // the ONLY barrier

  const int w8  = tid >> 6;                    // wave in block 0..7
  const int l   = tid & 63;
  const int p   = l >> 4;                      // lane quarter 0..3 (k-slice)
  const int c16 = l & 15;                      // token (qkv) / e-col / group-col
  const int g4  = c16 & 3;                     // group index for epilogue B-frags
  unsigned short* mybuf = wbuf_s[w8];

  const int nWT    = M >> 2;                   // wave-tiles (4 groups each)
  const int stride = gridDim.x * 8;
  for (int wt = blockIdx.x*8 + w8; wt < nWT; wt += stride){

    // ============ Phase A: direct A-frag load + LN1 (token = c16) ============
    const int s_ = c16 & 3;
    const int m  = wt*4 + (c16 >> 2);
    const float* rowp;
    if      (s_ == 0) rowp = z_cls;
    else if (s_ == 1) rowp = z_m + (size_t)m * 64;
    else if (s_ == 2) rowp = z_c + (size_t)m * 64;
    else              rowp = z_t + (size_t)m * 64;

    float xv[16];
    {
      float4 q0 = *(const float4*)(rowp + 8*p);
      float4 q1 = *(const float4*)(rowp + 8*p + 4);
      float4 q2 = *(const float4*)(rowp + 32 + 8*p);
      float4 q3 = *(const float4*)(rowp + 32 + 8*p + 4);
      xv[0]=q0.x; xv[1]=q0.y; xv[2]=q0.z; xv[3]=q0.w;
      xv[4]=q1.x; xv[5]=q1.y; xv[6]=q1.z; xv[7]=q1.w;
      xv[8]=q2.x; xv[9]=q2.y; xv[10]=q2.z; xv[11]=q2.w;
      xv[12]=q3.x; xv[13]=q3.y; xv[14]=q3.z; xv[15]=q3.w;
    }
    float sm = 0.f;
    #pragma unroll
    for (int i = 0; i < 16; ++i) sm += xv[i];
    sm += __shfl_xor(sm, 16); sm += __shfl_xor(sm, 32);
    float mu = sm * (1.f/64.f);
    float sq = 0.f;
    #pragma unroll
    for (int i = 0; i < 16; ++i){ float d = xv[i]-mu; sq = fmaf(d, d, sq); }
    sq += __shfl_xor(sq, 16); sq += __shfl_xor(sq, 32);
    float rstd = 1.f / sqrtf(sq * (1.f/64.f) + 1e-5f);

    short8 a0, a1;                             // A-frag: row=c16(token), k=8p+j
    #pragma unroll
    for (int j = 0; j < 8; ++j) a0[j] = (short)f2bf((xv[j]   - mu) * rstd);
    #pragma unroll
    for (int j = 0; j < 8; ++j) a1[j] = (short)f2bf((xv[8+j] - mu) * rstd);

    // ============ qkv MFMA: 24 MFMA, acc[n] = (e=c16+16n, token 4p+r) ========
    f32x4 acc[12];
    #pragma unroll
    for (int n = 0; n < 12; ++n) acc[n] = (f32x4){0.f,0.f,0.f,0.f};
    #pragma unroll
    for (int n = 0; n < 12; ++n){
      int e = c16 + 16*n;
      short8 b0 = *(const short8*)&ipw_s[SWZ((e*64 +      8*p)*2, e) >> 1];
      short8 b1v= *(const short8*)&ipw_s[SWZ((e*64 + 32 + 8*p)*2, e) >> 1];
      acc[n] = MFMA16(a0, b0, acc[n]);
      acc[n] = MFMA16(a1, b1v, acc[n]);
    }
    #pragma unroll
    for (int n = 0; n < 12; ++n){
      float bi = par_s[c16 + 16*n];
      #pragma unroll
      for (int r = 0; r < 4; ++r) acc[n][r] += bi;
    }

    // ============ attention (wave-local; group = p, channel = c16) ===========
    float awm[16];
    #pragma unroll
    for (int i = 0; i < 16; ++i) awm[i] = 0.f;
    float ctx4[4];
    #pragma unroll
    for (int h = 0; h < 4; ++h){
      float sc[16];
      #pragma unroll
      for (int q = 0; q < 4; ++q)
        #pragma unroll
        for (int u = 0; u < 4; ++u) sc[q*4+u] = acc[h][q] * acc[4+h][u];
      #pragma unroll
      for (int st = 0; st < 4; ++st){
        const int mask = 1 << st;
        #pragma unroll
        for (int i = 0; i < 16; ++i) sc[i] += __shfl_xor(sc[i], mask);
      }
      #pragma unroll
      for (int q = 0; q < 4; ++q){
        float s0 = sc[4*q+0]*0.25f, s1 = sc[4*q+1]*0.25f,
              s2 = sc[4*q+2]*0.25f, s3 = sc[4*q+3]*0.25f;
        float mx = fmaxf(fmaxf(s0,s1), fmaxf(s2,s3));
        s0 = __expf(s0-mx); s1 = __expf(s1-mx); s2 = __expf(s2-mx); s3 = __expf(s3-mx);
        float inv = 1.f/(s0+s1+s2+s3);
        s0*=inv; s1*=inv; s2*=inv; s3*=inv;
        sc[4*q+0]=s0; sc[4*q+1]=s1; sc[4*q+2]=s2; sc[4*q+3]=s3;
        awm[4*q+0]+=s0; awm[4*q+1]+=s1; awm[4*q+2]+=s2; awm[4*q+3]+=s3;
      }
      ctx4[h] = sc[0]*acc[8+h][0] + sc[1]*acc[8+h][1]
              + sc[2]*acc[8+h][2] + sc[3]*acc[8+h][3];
    }
    if (c16 == 0){
      float4* ap = (float4*)(aw_out + (size_t)(wt*4 + p)*16);
      ap[0] = make_float4(awm[0]*0.25f,  awm[1]*0.25f,  awm[2]*0.25f,  awm[3]*0.25f);
      ap[1] = make_float4(awm[4]*0.25f,  awm[5]*0.25f,  awm[6]*0.25f,  awm[7]*0.25f);
      ap[2] = make_float4(awm[8]*0.25f,  awm[9]*0.25f,  awm[10]*0.25f, awm[11]*0.25f);
      ap[3] = make_float4(awm[12]*0.25f, awm[13]*0.25f, awm[14]*0.25f, awm[15]*0.25f);
    }

    // ============ ctx relayout (wave-private LDS; DS in-order, no barrier) ===
    #pragma unroll
    for (int h = 0; h < 4; ++h)
      mybuf[p*64 + 16*h + c16] = f2bf(ctx4[h]);   // ctx[group p][dim 16h+c16]
    short8 cb0 = *(const short8*)&mybuf[g4*64 +      8*p];  // B: col=group, k=dim
    short8 cb1 = *(const short8*)&mybuf[g4*64 + 32 + 8*p];

    // ============ out-proj: 8 MFMA, D = (e=16mt+4p+r, col=group c16&3) =======
    f32x4 op[4];
    #pragma unroll
    for (int mt = 0; mt < 4; ++mt) op[mt] = (f32x4){0.f,0.f,0.f,0.f};
    #pragma unroll
    for (int mt = 0; mt < 4; ++mt){
      int er = 16*mt + c16;
      short8 A0 = *(const short8*)&ow_s[SWZ((er*64 +      8*p)*2, er) >> 1];
      short8 A1 = *(const short8*)&ow_s[SWZ((er*64 + 32 + 8*p)*2, er) >> 1];
      op[mt] = MFMA16(A0, cb0, op[mt]);
      op[mt] = MFMA16(A1, cb1, op[mt]);
    }
    float x0[16];
    #pragma unroll
    for (int mt = 0; mt < 4; ++mt){
      float4 z4 = *(const float4*)&par_s[192 + 16*mt + 4*p];
      x0[4*mt+0] = op[mt][0] + z4.x;
      x0[4*mt+1] = op[mt][1] + z4.y;
      x0[4*mt+2] = op[mt][2] + z4.z;
      x0[4*mt+3] = op[mt][3] + z4.w;
    }
    // LN2 stats (reduce over p via xor 16/32; gamma/beta folded into w1'/b1')
    float sm2 = 0.f;
    #pragma unroll
    for (int i = 0; i < 16; ++i) sm2 += x0[i];
    sm2 += __shfl_xor(sm2, 16); sm2 += __shfl_xor(sm2, 32);
    float mu2 = sm2 * (1.f/64.f);
    float sq2 = 0.f;
    #pragma unroll
    for (int i = 0; i < 16; ++i){ float d = x0[i]-mu2; sq2 = fmaf(d, d, sq2); }
    sq2 += __shfl_xor(sq2, 16); sq2 += __shfl_xor(sq2, 32);
    float rstd2 = 1.f / sqrtf(sq2 * (1.f/64.f) + 1e-5f);
    if (c16 < 4){                               // write xhat2 (bf16) for group c16
      #pragma unroll
      for (int mt = 0; mt < 4; ++mt){
        us4 v;
        #pragma unroll
        for (int r = 0; r < 4; ++r)
          v[r] = f2bf((x0[4*mt+r] - mu2) * rstd2);
        *(us4*)&mybuf[c16*64 + 16*mt + 4*p] = v;
      }
    }

    // ============ FFN1: 16 MFMA, D = (e1=16mt'+4p+r, col=group) ==============
    short8 yb0 = *(const short8*)&mybuf[g4*64 +      8*p];
    short8 yb1 = *(const short8*)&mybuf[g4*64 + 32 + 8*p];
    f32x4 f1[8];
    #pragma unroll
    for (int mt = 0; mt < 8; ++mt) f1[mt] = (f32x4){0.f,0.f,0.f,0.f};
    #pragma unroll
    for (int mt = 0; mt < 8; ++mt){
      int er = 16*mt + c16;
      short8 A0 = *(const short8*)&w1_s[SWZ((er*64 +      8*p)*2, er) >> 1];
      short8 A1 = *(const short8*)&w1_s[SWZ((er*64 + 32 + 8*p)*2, er) >> 1];
      f1[mt] = MFMA16(A0, yb0, f1[mt]);
      f1[mt] = MFMA16(A1, yb1, f1[mt]);
    }
    if (c16 < 4){                               // +b1' -> GELU -> h1 bf16
      #pragma unroll
      for (int mt = 0; mt < 8; ++mt){
        float4 b4 = *(const float4*)&par_s[256 + 16*mt + 4*p];
        us4 v;
        v[0] = f2bf(fast_gelu(f1[mt][0] + b4.x));
        v[1] = f2bf(fast_gelu(f1[mt][1] + b4.y));
        v[2] = f2bf(fast_gelu(f1[mt][2] + b4.z));
        v[3] = f2bf(fast_gelu(f1[mt][3] + b4.w));
        *(us4*)&mybuf[c16*128 + 16*mt + 4*p] = v;
      }
    }

    // ============ FFN2: 16 MFMA + residual + store ===========================
    f32x4 f2a[4];
    #pragma unroll
    for (int mt = 0; mt < 4; ++mt) f2a[mt] = (f32x4){0.f,0.f,0.f,0.f};
    #pragma unroll
    for (int mt = 0; mt < 4; ++mt){
      int ar = 16*mt + c16;
      #pragma unroll
      for (int ks = 0; ks < 4; ++ks){
        short8 A = *(const short8*)&w2_s[SWZ((ar*128 + 32*ks + 8*p)*2, ar) >> 1];
        short8 B = *(const short8*)&mybuf[g4*128 + 32*ks + 8*p];
        f2a[mt] = MFMA16(A, B, f2a[mt]);
      }
    }
    if (c16 < 4){
      float* orow = h_out + (size_t)(wt*4 + c16)*64;
      #pragma unroll
      for (int mt = 0; mt < 4; ++mt){
        float4 b4 = *(const float4*)&par_s[384 + 16*mt + 4*p];
        float4 ov;
        ov.x = f2a[mt][0] + x0[4*mt+0] + b4.x;
        ov.y = f2a[mt][1] + x0[4*mt+1] + b4.y;
        ov.z = f2a[mt][2] + x0[4*mt+2] + b4.z;
        ov.w = f2a[mt][3] + x0[4*mt+3] + b4.w;
        *(float4*)(orow + 16*mt + 4*p) = ov;
      }
    }
  }
}

extern "C" void kernel_launch(void* const* d_in, const int* in_sizes, int n_in,
                              void* d_out, int out_size, void* d_ws, size_t ws_size,
                              hipStream_t stream) {
  const float* z_m   = (const float*)d_in[0];
  const float* z_c   = (const float*)d_in[1];
  const float* z_t   = (const float*)d_in[2];
  const float* z_cls = (const float*)d_in[3];
  const float* ipw   = (const float*)d_in[4];
  const float* ipb   = (const float*)d_in[5];
  const float* out_w = (const float*)d_in[6];
  const float* out_b = (const float*)d_in[7];
  const float* ln1_g = (const float*)d_in[8];
  const float* ln1_b = (const float*)d_in[9];
  const float* ln2_g = (const float*)d_in[10];
  const float* ln2_b = (const float*)d_in[11];
  const float* w1    = (const float*)d_in[12];
  const float* b1    = (const float*)d_in[13];
  const float* w2    = (const float*)d_in[14];
  const float* b2    = (const float*)d_in[15];

  const int M = in_sizes[0] / 64;          // B*N groups (160000, divisible by 4)
  float* h_out  = (float*)d_out;           // (M,64)
  float* aw_out = h_out + (size_t)M * 64;  // (M,4,4)

  hipLaunchKernelGGL(mt_kernel, dim3(512), dim3(512), 0, stream,
                     z_m, z_c, z_t, z_cls, ipw, ipb, out_w, out_b,
                     ln1_g, ln1_b, ln2_g, ln2_b, w1, b1, w2, b2,
                     h_out, aw_out, M);
}